// Round 1
// baseline (877.101 us; speedup 1.0000x reference)
//
#include <hip/hip_runtime.h>
#include <math.h>

// ---------------------------------------------------------------------------
// Problem constants (from reference)
// ---------------------------------------------------------------------------
#define HIDDEN 64
#define HEADS 2
#define NCOLS 448          // 3*HEADS*HIDDEN (q,k,v) + HIDDEN (skip) = 128*3+64
#define N_GRAPHS 64
#define LN_EPS 1e-5f

// ---------------------------------------------------------------------------
// Weight pack: Wcat[K][448] = [Wq | Wk | Wv | Ws], bcat[448]
// ---------------------------------------------------------------------------
__global__ void pack_kernel(const float* __restrict__ Wq, const float* __restrict__ Wk,
                            const float* __restrict__ Wv, const float* __restrict__ Ws,
                            const float* __restrict__ bq, const float* __restrict__ bk,
                            const float* __restrict__ bv, const float* __restrict__ bs,
                            float* __restrict__ Wcat, float* __restrict__ bcat, int K)
{
    int idx = blockIdx.x * 256 + threadIdx.x;
    int total = K * NCOLS;
    if (idx < total) {
        int r = idx / NCOLS, c = idx - r * NCOLS;
        float v;
        if      (c < 128) v = Wq[r * 128 + c];
        else if (c < 256) v = Wk[r * 128 + (c - 128)];
        else if (c < 384) v = Wv[r * 128 + (c - 256)];
        else              v = Ws[r * 64  + (c - 384)];
        Wcat[idx] = v;
    }
    if (idx < NCOLS) {
        float b;
        if      (idx < 128) b = bq[idx];
        else if (idx < 256) b = bk[idx - 128];
        else if (idx < 384) b = bv[idx - 256];
        else                b = bs[idx - 384];
        bcat[idx] = b;
    }
}

// ---------------------------------------------------------------------------
// fp32 tiled GEMM with bias: C[M,448] = A[M,K] @ B[K,448] + bias
// BM=BN=64, BK=16, 256 threads, 4x4 microtile / thread
// ---------------------------------------------------------------------------
#define BM 64
#define BN 64
#define BK 16

__global__ __launch_bounds__(256) void gemm_bias_kernel(
    const float* __restrict__ A, const float* __restrict__ B,
    const float* __restrict__ bias, float* __restrict__ C,
    int M, int K, int Ncols)
{
    __shared__ __align__(16) float As[BK][BM + 4]; // transposed A tile, padded
    __shared__ __align__(16) float Bs[BK][BN];

    int tid = threadIdx.x;
    int tx = tid & 15;    // 0..15 -> 4 cols each
    int ty = tid >> 4;    // 0..15 -> 4 rows each
    int row0 = blockIdx.y * BM;
    int col0 = blockIdx.x * BN;

    float acc[4][4] = {};

    for (int k0 = 0; k0 < K; k0 += BK) {
        // A tile: 64 rows x 16 k, elem (m, kk), linear li = tid + i*256
        #pragma unroll
        for (int i = 0; i < 4; ++i) {
            int li = tid + i * 256;
            int m  = li >> 4;
            int kk = li & 15;
            int gr = row0 + m;
            As[kk][m] = (gr < M) ? A[(size_t)gr * K + k0 + kk] : 0.0f;
        }
        // B tile: 16 k x 64 cols
        #pragma unroll
        for (int i = 0; i < 4; ++i) {
            int li = tid + i * 256;
            int kk = li >> 6;
            int c  = li & 63;
            Bs[kk][c] = B[(size_t)(k0 + kk) * Ncols + col0 + c];
        }
        __syncthreads();
        #pragma unroll
        for (int kk = 0; kk < BK; ++kk) {
            float4 a4 = *(const float4*)&As[kk][ty * 4];
            float4 b4 = *(const float4*)&Bs[kk][tx * 4];
            float av[4] = {a4.x, a4.y, a4.z, a4.w};
            float bv[4] = {b4.x, b4.y, b4.z, b4.w};
            #pragma unroll
            for (int i = 0; i < 4; ++i)
                #pragma unroll
                for (int j = 0; j < 4; ++j)
                    acc[i][j] += av[i] * bv[j];
        }
        __syncthreads();
    }

    #pragma unroll
    for (int i = 0; i < 4; ++i) {
        int r = row0 + ty * 4 + i;
        if (r >= M) continue;
        #pragma unroll
        for (int j = 0; j < 4; ++j) {
            int c = col0 + tx * 4 + j;
            C[(size_t)r * Ncols + c] = acc[i][j] + bias[c];
        }
    }
}

// ---------------------------------------------------------------------------
// CSR build: histogram -> single-block scan -> scatter (src sorted by dst)
// ---------------------------------------------------------------------------
__global__ void hist_kernel(const int* __restrict__ dst, int* __restrict__ counts, int E)
{
    int i = blockIdx.x * 256 + threadIdx.x;
    if (i < E) atomicAdd(&counts[dst[i]], 1);
}

__global__ __launch_bounds__(1024) void scan_kernel(const int* __restrict__ counts,
                                                    int* __restrict__ row_ptr,
                                                    int* __restrict__ cursor, int N)
{
    __shared__ int sums[1024];
    int t = threadIdx.x;
    int chunk = (N + 1023) / 1024;
    int start = t * chunk;
    int end   = min(start + chunk, N);
    int s = 0;
    for (int i = start; i < end; ++i) s += counts[i];
    sums[t] = s;
    __syncthreads();
    for (int off = 1; off < 1024; off <<= 1) {
        int v = (t >= off) ? sums[t - off] : 0;
        __syncthreads();
        sums[t] += v;
        __syncthreads();
    }
    int prefix = (t == 0) ? 0 : sums[t - 1];
    for (int i = start; i < end; ++i) {
        row_ptr[i] = prefix;
        cursor[i]  = prefix;
        prefix += counts[i];
    }
    if (t == 1023) row_ptr[N] = sums[1023];
}

__global__ void scatter_kernel(const int* __restrict__ ei, int* __restrict__ cursor,
                               int* __restrict__ src_sorted, int E)
{
    int i = blockIdx.x * 256 + threadIdx.x;
    if (i < E) {
        int d = ei[E + i];                    // dst
        int pos = atomicAdd(&cursor[d], 1);
        src_sorted[pos] = ei[i];              // src
    }
}

// ---------------------------------------------------------------------------
// Fused edge kernel: one wave per dst node.
// Online softmax over incoming edges, head-mean + skip + ReLU + optional LN.
// qkvs row layout: [q_h0(64) q_h1(64) k_h0 k_h1 v_h0 v_h1 skip(64)]
// ---------------------------------------------------------------------------
__device__ __forceinline__ float wave_sum(float v)
{
    #pragma unroll
    for (int m = 32; m; m >>= 1) v += __shfl_xor(v, m);
    return v;
}

__global__ __launch_bounds__(256) void edge_conv_kernel(
    const float* __restrict__ qkvs, const int* __restrict__ row_ptr,
    const int* __restrict__ src_sorted, const float* __restrict__ gamma,
    const float* __restrict__ beta, float* __restrict__ hout, int N, int do_ln)
{
    int wave = threadIdx.x >> 6;
    int lane = threadIdx.x & 63;
    int node = blockIdx.x * 4 + wave;
    if (node >= N) return;

    const float* base = qkvs + (size_t)node * NCOLS;
    float q0 = base[lane];
    float q1 = base[64 + lane];
    float skip = base[384 + lane];

    int e0 = row_ptr[node], e1 = row_ptr[node + 1];

    float m0 = -1e30f, m1 = -1e30f;
    float s0 = 0.f, s1 = 0.f, a0 = 0.f, a1 = 0.f;

    for (int e = e0; e < e1; ++e) {
        int j = src_sorted[e];
        const float* jb = qkvs + (size_t)j * NCOLS;
        float k0 = jb[128 + lane], k1 = jb[192 + lane];
        float v0 = jb[256 + lane], v1 = jb[320 + lane];
        float p0 = q0 * k0, p1 = q1 * k1;
        #pragma unroll
        for (int m = 32; m; m >>= 1) {
            p0 += __shfl_xor(p0, m);
            p1 += __shfl_xor(p1, m);
        }
        float sc0 = p0 * 0.125f;   // 1/sqrt(64)
        float sc1 = p1 * 0.125f;
        float nm0 = fmaxf(m0, sc0);
        float f0 = __expf(m0 - nm0);
        float w0 = __expf(sc0 - nm0);
        s0 = s0 * f0 + w0;
        a0 = a0 * f0 + w0 * v0;
        m0 = nm0;
        float nm1 = fmaxf(m1, sc1);
        float f1 = __expf(m1 - nm1);
        float w1 = __expf(sc1 - nm1);
        s1 = s1 * f1 + w1;
        a1 = a1 * f1 + w1 * v1;
        m1 = nm1;
    }

    float o = (e1 > e0) ? (0.5f * (a0 / s0 + a1 / s1) + skip) : skip;
    o = fmaxf(o, 0.f);

    if (do_ln) {
        float mu = wave_sum(o) * (1.0f / 64.0f);
        float d = o - mu;
        float var = wave_sum(d * d) * (1.0f / 64.0f);
        o = d * rsqrtf(var + LN_EPS) * gamma[lane] + beta[lane];
    }
    hout[(size_t)node * HIDDEN + lane] = o;
}

// ---------------------------------------------------------------------------
// Pooling: batch is sorted; per-block register accumulation, rare atomic flush
// ---------------------------------------------------------------------------
#define POOL_NODES 256
__global__ __launch_bounds__(64) void pool_kernel(const float* __restrict__ h,
                                                  const int* __restrict__ batch,
                                                  float* __restrict__ pooled,
                                                  float* __restrict__ cnt, int N)
{
    int lane = threadIdx.x;
    int start = blockIdx.x * POOL_NODES;
    if (start >= N) return;
    int end = min(start + POOL_NODES, N);
    float acc = 0.f;
    int cur = batch[start];
    int c = 0;
    for (int i = start; i < end; ++i) {
        int b = batch[i];
        if (b != cur) {
            atomicAdd(&pooled[cur * HIDDEN + lane], acc);
            if (lane == 0) atomicAdd(&cnt[cur], (float)c);
            acc = 0.f; c = 0; cur = b;
        }
        acc += h[(size_t)i * HIDDEN + lane];
        ++c;
    }
    atomicAdd(&pooled[cur * HIDDEN + lane], acc);
    if (lane == 0) atomicAdd(&cnt[cur], (float)c);
}

__global__ void final_kernel(const float* __restrict__ pooled, const float* __restrict__ cnt,
                             const float* __restrict__ Wp, const float* __restrict__ bp,
                             float* __restrict__ out)
{
    int g = threadIdx.x;   // 64 graphs
    float c = fmaxf(cnt[g], 1.0f);
    float s = 0.f;
    for (int d = 0; d < HIDDEN; ++d) s += pooled[g * HIDDEN + d] * Wp[d];
    out[g] = s / c + bp[0];
}

// ---------------------------------------------------------------------------
// Host launcher
// ---------------------------------------------------------------------------
extern "C" void kernel_launch(void* const* d_in, const int* in_sizes, int n_in,
                              void* d_out, int out_size, void* d_ws, size_t ws_size,
                              hipStream_t stream)
{
    const float* x    = (const float*)d_in[0];
    const int*   ei   = (const int*)d_in[1];
    const int*   batch= (const int*)d_in[2];

    const float* Wl[3][4];  // Wq, Wk, Wv, Ws
    const float* bl[3][4];  // bq, bk, bv, bs
    for (int l = 0; l < 3; ++l) {
        int b = 3 + l * 8;
        Wl[l][0] = (const float*)d_in[b + 0]; bl[l][0] = (const float*)d_in[b + 1];
        Wl[l][1] = (const float*)d_in[b + 2]; bl[l][1] = (const float*)d_in[b + 3];
        Wl[l][2] = (const float*)d_in[b + 4]; bl[l][2] = (const float*)d_in[b + 5];
        Wl[l][3] = (const float*)d_in[b + 6]; bl[l][3] = (const float*)d_in[b + 7];
    }
    const float* g0    = (const float*)d_in[27];
    const float* beta0 = (const float*)d_in[28];
    const float* g1    = (const float*)d_in[29];
    const float* beta1 = (const float*)d_in[30];
    const float* Wp    = (const float*)d_in[31];
    const float* bp    = (const float*)d_in[32];

    const int N = in_sizes[0] / 128;   // 50000
    const int E = in_sizes[1] / 2;     // 800000

    // workspace carve (256B aligned)
    size_t off = 0;
    auto carve = [&](size_t bytes) -> char* {
        char* p = (char*)d_ws + off;
        off = (off + bytes + 255) & ~(size_t)255;
        return p;
    };
    float* qkvs     = (float*)carve((size_t)N * NCOLS * 4);
    float* h        = (float*)carve((size_t)N * HIDDEN * 4);
    float* Wcat     = (float*)carve(128 * NCOLS * 4);
    float* bcat     = (float*)carve(NCOLS * 4);
    int*   counts   = (int*)carve((size_t)N * 4);
    int*   row_ptr  = (int*)carve((size_t)(N + 1) * 4);
    int*   cursor   = (int*)carve((size_t)N * 4);
    int*   src_sorted = (int*)carve((size_t)E * 4);
    float* pooled   = (float*)carve((size_t)(N_GRAPHS * HIDDEN + N_GRAPHS) * 4);
    float* cntf     = pooled + N_GRAPHS * HIDDEN;

    // ---- CSR build (dst is layer-invariant) ----
    hipMemsetAsync(counts, 0, (size_t)N * 4, stream);
    hist_kernel<<<(E + 255) / 256, 256, 0, stream>>>(ei + E, counts, E);
    scan_kernel<<<1, 1024, 0, stream>>>(counts, row_ptr, cursor, N);
    scatter_kernel<<<(E + 255) / 256, 256, 0, stream>>>(ei, cursor, src_sorted, E);

    // ---- 3 TransformerConv layers ----
    for (int l = 0; l < 3; ++l) {
        int K = (l == 0) ? 128 : 64;
        const float* Ain = (l == 0) ? x : h;
        int packTot = K * NCOLS;
        pack_kernel<<<(packTot + 255) / 256, 256, 0, stream>>>(
            Wl[l][0], Wl[l][1], Wl[l][2], Wl[l][3],
            bl[l][0], bl[l][1], bl[l][2], bl[l][3], Wcat, bcat, K);
        dim3 ggrid(NCOLS / BN, (N + BM - 1) / BM);
        gemm_bias_kernel<<<ggrid, 256, 0, stream>>>(Ain, Wcat, bcat, qkvs, N, K, NCOLS);
        int do_ln = (l < 2) ? 1 : 0;
        const float* gg = (l == 0) ? g0 : g1;
        const float* bb = (l == 0) ? beta0 : beta1;
        edge_conv_kernel<<<(N + 3) / 4, 256, 0, stream>>>(
            qkvs, row_ptr, src_sorted, gg, bb, h, N, do_ln);
    }

    // ---- global mean pool + head ----
    hipMemsetAsync(pooled, 0, (size_t)(N_GRAPHS * HIDDEN + N_GRAPHS) * 4, stream);
    pool_kernel<<<(N + POOL_NODES - 1) / POOL_NODES, 64, 0, stream>>>(h, batch, pooled, cntf, N);
    final_kernel<<<1, 64, 0, stream>>>(pooled, cntf, Wp, bp, (float*)d_out);
}

// Round 2
// 807.149 us; speedup vs baseline: 1.0867x; 1.0867x over previous
//
#include <hip/hip_runtime.h>
#include <math.h>

// ---------------------------------------------------------------------------
// Problem constants (from reference)
// ---------------------------------------------------------------------------
#define HIDDEN 64
#define HEADS 2
#define NCOLS 448          // 3*HEADS*HIDDEN (q,k,v) + HIDDEN (skip)
#define N_GRAPHS 64
#define LN_EPS 1e-5f

// ---------------------------------------------------------------------------
// Weight pack: Wcat[K][448] = [Wq | Wk | Wv | Ws], bcat[448]
// ---------------------------------------------------------------------------
__global__ void pack_kernel(const float* __restrict__ Wq, const float* __restrict__ Wk,
                            const float* __restrict__ Wv, const float* __restrict__ Ws,
                            const float* __restrict__ bq, const float* __restrict__ bk,
                            const float* __restrict__ bv, const float* __restrict__ bs,
                            float* __restrict__ Wcat, float* __restrict__ bcat, int K)
{
    int idx = blockIdx.x * 256 + threadIdx.x;
    int total = K * NCOLS;
    if (idx < total) {
        int r = idx / NCOLS, c = idx - r * NCOLS;
        float v;
        if      (c < 128) v = Wq[r * 128 + c];
        else if (c < 256) v = Wk[r * 128 + (c - 128)];
        else if (c < 384) v = Wv[r * 128 + (c - 256)];
        else              v = Ws[r * 64  + (c - 384)];
        Wcat[idx] = v;
    }
    if (idx < NCOLS) {
        float b;
        if      (idx < 128) b = bq[idx];
        else if (idx < 256) b = bk[idx - 128];
        else if (idx < 384) b = bv[idx - 256];
        else                b = bs[idx - 384];
        bcat[idx] = b;
    }
}

// ---------------------------------------------------------------------------
// fp32 tiled GEMM with bias: C[M,448] = A[M,K] @ B[K,448] + bias
// BM=128, BN=64, BK=16, 256 threads, 8x4 microtile / thread.
// a-reads are wave-broadcast (same addr across 16 lanes) -> no bank conflict.
// ---------------------------------------------------------------------------
#define BM 128
#define BN 64
#define BK 16

__global__ __launch_bounds__(256) void gemm_bias_kernel(
    const float* __restrict__ A, const float* __restrict__ B,
    const float* __restrict__ bias, float* __restrict__ C,
    int M, int K, int Ncols)
{
    __shared__ __align__(16) float As[BK][BM + 4]; // k-major (transposed) A tile
    __shared__ __align__(16) float Bs[BK][BN];

    int tid = threadIdx.x;
    int tx = tid & 15;    // 0..15 -> 4 cols each
    int ty = tid >> 4;    // 0..15 -> 8 rows each
    int row0 = blockIdx.y * BM;
    int col0 = blockIdx.x * BN;

    float acc[8][4] = {};

    for (int k0 = 0; k0 < K; k0 += BK) {
        // A tile: 128 rows x 16 k = 512 float4 chunks; 2 per thread
        #pragma unroll
        for (int i = 0; i < 2; ++i) {
            int f   = tid + i * 256;          // float4 id
            int m   = f >> 2;                 // 0..127
            int kc  = f & 3;                  // 0..3 (k-chunk of 4)
            int gr  = row0 + m;
            float4 v = make_float4(0.f, 0.f, 0.f, 0.f);
            if (gr < M) v = *(const float4*)&A[(size_t)gr * K + k0 + kc * 4];
            As[kc * 4 + 0][m] = v.x;
            As[kc * 4 + 1][m] = v.y;
            As[kc * 4 + 2][m] = v.z;
            As[kc * 4 + 3][m] = v.w;
        }
        // B tile: 16 k x 64 cols = 256 float4; 1 per thread
        {
            int kk = tid >> 4;
            int c4 = tid & 15;
            *(float4*)&Bs[kk][c4 * 4] =
                *(const float4*)&B[(size_t)(k0 + kk) * Ncols + col0 + c4 * 4];
        }
        __syncthreads();
        #pragma unroll
        for (int kk = 0; kk < BK; ++kk) {
            float4 a0 = *(const float4*)&As[kk][ty * 8];
            float4 a1 = *(const float4*)&As[kk][ty * 8 + 4];
            float4 b4 = *(const float4*)&Bs[kk][tx * 4];
            float av[8] = {a0.x, a0.y, a0.z, a0.w, a1.x, a1.y, a1.z, a1.w};
            float bv[4] = {b4.x, b4.y, b4.z, b4.w};
            #pragma unroll
            for (int i = 0; i < 8; ++i)
                #pragma unroll
                for (int j = 0; j < 4; ++j)
                    acc[i][j] = fmaf(av[i], bv[j], acc[i][j]);
        }
        __syncthreads();
    }

    float4 bsv = *(const float4*)&bias[col0 + tx * 4];
    float bb[4] = {bsv.x, bsv.y, bsv.z, bsv.w};
    #pragma unroll
    for (int i = 0; i < 8; ++i) {
        int r = row0 + ty * 8 + i;
        if (r >= M) continue;
        float4 o = make_float4(acc[i][0] + bb[0], acc[i][1] + bb[1],
                               acc[i][2] + bb[2], acc[i][3] + bb[3]);
        *(float4*)&C[(size_t)r * Ncols + col0 + tx * 4] = o;
    }
}

// ---------------------------------------------------------------------------
// CSR build: histogram -> single-block scan -> scatter (src sorted by dst)
// ---------------------------------------------------------------------------
__global__ void hist_kernel(const int* __restrict__ dst, int* __restrict__ counts, int E)
{
    int i = blockIdx.x * 256 + threadIdx.x;
    if (i < E) atomicAdd(&counts[dst[i]], 1);
}

__global__ __launch_bounds__(1024) void scan_kernel(const int* __restrict__ counts,
                                                    int* __restrict__ row_ptr,
                                                    int* __restrict__ cursor, int N)
{
    __shared__ int sums[1024];
    int t = threadIdx.x;
    int chunk = (N + 1023) / 1024;
    int start = t * chunk;
    int end   = min(start + chunk, N);
    int s = 0;
    for (int i = start; i < end; ++i) s += counts[i];
    sums[t] = s;
    __syncthreads();
    for (int off = 1; off < 1024; off <<= 1) {
        int v = (t >= off) ? sums[t - off] : 0;
        __syncthreads();
        sums[t] += v;
        __syncthreads();
    }
    int prefix = (t == 0) ? 0 : sums[t - 1];
    for (int i = start; i < end; ++i) {
        row_ptr[i] = prefix;
        cursor[i]  = prefix;
        prefix += counts[i];
    }
    if (t == 1023) row_ptr[N] = sums[1023];
}

__global__ void scatter_kernel(const int* __restrict__ ei, int* __restrict__ cursor,
                               int* __restrict__ src_sorted, int E)
{
    int i = blockIdx.x * 256 + threadIdx.x;
    if (i < E) {
        int d = ei[E + i];                    // dst
        int pos = atomicAdd(&cursor[d], 1);
        src_sorted[pos] = ei[i];              // src
    }
}

// ---------------------------------------------------------------------------
// Fused edge kernel: one wave per dst node, 4 edge-groups x 16 lanes.
// Each lane holds float4 (4 dims); in-group shfl reduce for dot products;
// flash-state merge across groups at the end. Head-mean + skip + ReLU + LN.
// qkvs row layout: [q_h0(64) q_h1(64) k_h0 k_h1 v_h0 v_h1 skip(64)]
// ---------------------------------------------------------------------------
__device__ __forceinline__ float grp_sum16(float v)
{
    #pragma unroll
    for (int m = 8; m; m >>= 1) v += __shfl_xor(v, m);
    return v;
}

__global__ __launch_bounds__(256) void edge_conv_kernel(
    const float* __restrict__ qkvs, const int* __restrict__ row_ptr,
    const int* __restrict__ src_sorted, const float* __restrict__ gamma,
    const float* __restrict__ beta, float* __restrict__ hout, int N, int do_ln)
{
    int wave = threadIdx.x >> 6;
    int lane = threadIdx.x & 63;
    int g    = lane >> 4;        // edge-group 0..3
    int sub  = lane & 15;        // dim-chunk 0..15 (4 dims each)
    int node = blockIdx.x * 4 + wave;
    if (node >= N) return;

    const float* base = qkvs + (size_t)node * NCOLS;
    float4 q0 = *(const float4*)&base[sub * 4];
    float4 q1 = *(const float4*)&base[64 + sub * 4];

    int e0 = row_ptr[node], e1 = row_ptr[node + 1];

    float  m0 = -1e30f, m1 = -1e30f;
    float  s0 = 0.f, s1 = 0.f;
    float4 a0 = make_float4(0.f, 0.f, 0.f, 0.f);
    float4 a1 = make_float4(0.f, 0.f, 0.f, 0.f);

    for (int e = e0 + g; e < e1; e += 4) {
        int j = src_sorted[e];
        const float* jb = qkvs + (size_t)j * NCOLS;
        float4 k0 = *(const float4*)&jb[128 + sub * 4];
        float4 k1 = *(const float4*)&jb[192 + sub * 4];
        float4 v0 = *(const float4*)&jb[256 + sub * 4];
        float4 v1 = *(const float4*)&jb[320 + sub * 4];

        float p0 = q0.x * k0.x + q0.y * k0.y + q0.z * k0.z + q0.w * k0.w;
        float p1 = q1.x * k1.x + q1.y * k1.y + q1.z * k1.z + q1.w * k1.w;
        #pragma unroll
        for (int m = 8; m; m >>= 1) {
            p0 += __shfl_xor(p0, m);
            p1 += __shfl_xor(p1, m);
        }
        float sc0 = p0 * 0.125f;   // 1/sqrt(64)
        float sc1 = p1 * 0.125f;

        float nm0 = fmaxf(m0, sc0);
        float f0  = __expf(m0 - nm0);
        float w0  = __expf(sc0 - nm0);
        s0 = s0 * f0 + w0;
        a0.x = a0.x * f0 + w0 * v0.x;
        a0.y = a0.y * f0 + w0 * v0.y;
        a0.z = a0.z * f0 + w0 * v0.z;
        a0.w = a0.w * f0 + w0 * v0.w;
        m0 = nm0;

        float nm1 = fmaxf(m1, sc1);
        float f1  = __expf(m1 - nm1);
        float w1  = __expf(sc1 - nm1);
        s1 = s1 * f1 + w1;
        a1.x = a1.x * f1 + w1 * v1.x;
        a1.y = a1.y * f1 + w1 * v1.y;
        a1.z = a1.z * f1 + w1 * v1.z;
        a1.w = a1.w * f1 + w1 * v1.w;
        m1 = nm1;
    }

    // merge flash states across the 4 groups (xor 16, then 32)
    #pragma unroll
    for (int off = 16; off <= 32; off <<= 1) {
        float mo0 = __shfl_xor(m0, off);
        float so0 = __shfl_xor(s0, off);
        float4 ao0;
        ao0.x = __shfl_xor(a0.x, off); ao0.y = __shfl_xor(a0.y, off);
        ao0.z = __shfl_xor(a0.z, off); ao0.w = __shfl_xor(a0.w, off);
        float nm = fmaxf(m0, mo0);
        float fa = __expf(m0 - nm), fb = __expf(mo0 - nm);
        s0 = s0 * fa + so0 * fb;
        a0.x = a0.x * fa + ao0.x * fb; a0.y = a0.y * fa + ao0.y * fb;
        a0.z = a0.z * fa + ao0.z * fb; a0.w = a0.w * fa + ao0.w * fb;
        m0 = nm;

        float mo1 = __shfl_xor(m1, off);
        float so1 = __shfl_xor(s1, off);
        float4 ao1;
        ao1.x = __shfl_xor(a1.x, off); ao1.y = __shfl_xor(a1.y, off);
        ao1.z = __shfl_xor(a1.z, off); ao1.w = __shfl_xor(a1.w, off);
        nm = fmaxf(m1, mo1);
        fa = __expf(m1 - nm); fb = __expf(mo1 - nm);
        s1 = s1 * fa + so1 * fb;
        a1.x = a1.x * fa + ao1.x * fb; a1.y = a1.y * fa + ao1.y * fb;
        a1.z = a1.z * fa + ao1.z * fb; a1.w = a1.w * fa + ao1.w * fb;
        m1 = nm;
    }

    float4 skip = *(const float4*)&base[384 + sub * 4];
    float4 o;
    if (e1 > e0) {
        float r0 = 0.5f / s0, r1 = 0.5f / s1;
        o.x = a0.x * r0 + a1.x * r1 + skip.x;
        o.y = a0.y * r0 + a1.y * r1 + skip.y;
        o.z = a0.z * r0 + a1.z * r1 + skip.z;
        o.w = a0.w * r0 + a1.w * r1 + skip.w;
    } else {
        o = skip;
    }
    o.x = fmaxf(o.x, 0.f); o.y = fmaxf(o.y, 0.f);
    o.z = fmaxf(o.z, 0.f); o.w = fmaxf(o.w, 0.f);

    if (do_ln) {
        float mu = grp_sum16(o.x + o.y + o.z + o.w) * (1.0f / 64.0f);
        float dx = o.x - mu, dy = o.y - mu, dz = o.z - mu, dw = o.w - mu;
        float var = grp_sum16(dx * dx + dy * dy + dz * dz + dw * dw) * (1.0f / 64.0f);
        float rs = rsqrtf(var + LN_EPS);
        float4 gm = *(const float4*)&gamma[sub * 4];
        float4 bt = *(const float4*)&beta[sub * 4];
        o.x = dx * rs * gm.x + bt.x;
        o.y = dy * rs * gm.y + bt.y;
        o.z = dz * rs * gm.z + bt.z;
        o.w = dw * rs * gm.w + bt.w;
    }
    if (g == 0)
        *(float4*)&hout[(size_t)node * HIDDEN + sub * 4] = o;
}

// ---------------------------------------------------------------------------
// Pooling: batch is sorted; per-block register accumulation, rare atomic flush
// ---------------------------------------------------------------------------
#define POOL_NODES 256
__global__ __launch_bounds__(64) void pool_kernel(const float* __restrict__ h,
                                                  const int* __restrict__ batch,
                                                  float* __restrict__ pooled,
                                                  float* __restrict__ cnt, int N)
{
    int lane = threadIdx.x;
    int start = blockIdx.x * POOL_NODES;
    if (start >= N) return;
    int end = min(start + POOL_NODES, N);
    float acc = 0.f;
    int cur = batch[start];
    int c = 0;
    for (int i = start; i < end; ++i) {
        int b = batch[i];
        if (b != cur) {
            atomicAdd(&pooled[cur * HIDDEN + lane], acc);
            if (lane == 0) atomicAdd(&cnt[cur], (float)c);
            acc = 0.f; c = 0; cur = b;
        }
        acc += h[(size_t)i * HIDDEN + lane];
        ++c;
    }
    atomicAdd(&pooled[cur * HIDDEN + lane], acc);
    if (lane == 0) atomicAdd(&cnt[cur], (float)c);
}

__global__ void final_kernel(const float* __restrict__ pooled, const float* __restrict__ cnt,
                             const float* __restrict__ Wp, const float* __restrict__ bp,
                             float* __restrict__ out)
{
    int g = threadIdx.x;   // 64 graphs
    float c = fmaxf(cnt[g], 1.0f);
    float s = 0.f;
    for (int d = 0; d < HIDDEN; ++d) s += pooled[g * HIDDEN + d] * Wp[d];
    out[g] = s / c + bp[0];
}

// ---------------------------------------------------------------------------
// Host launcher
// ---------------------------------------------------------------------------
extern "C" void kernel_launch(void* const* d_in, const int* in_sizes, int n_in,
                              void* d_out, int out_size, void* d_ws, size_t ws_size,
                              hipStream_t stream)
{
    const float* x    = (const float*)d_in[0];
    const int*   ei   = (const int*)d_in[1];
    const int*   batch= (const int*)d_in[2];

    const float* Wl[3][4];  // Wq, Wk, Wv, Ws
    const float* bl[3][4];  // bq, bk, bv, bs
    for (int l = 0; l < 3; ++l) {
        int b = 3 + l * 8;
        Wl[l][0] = (const float*)d_in[b + 0]; bl[l][0] = (const float*)d_in[b + 1];
        Wl[l][1] = (const float*)d_in[b + 2]; bl[l][1] = (const float*)d_in[b + 3];
        Wl[l][2] = (const float*)d_in[b + 4]; bl[l][2] = (const float*)d_in[b + 5];
        Wl[l][3] = (const float*)d_in[b + 6]; bl[l][3] = (const float*)d_in[b + 7];
    }
    const float* g0    = (const float*)d_in[27];
    const float* beta0 = (const float*)d_in[28];
    const float* g1    = (const float*)d_in[29];
    const float* beta1 = (const float*)d_in[30];
    const float* Wp    = (const float*)d_in[31];
    const float* bp    = (const float*)d_in[32];

    const int N = in_sizes[0] / 128;   // 50000
    const int E = in_sizes[1] / 2;     // 800000

    // workspace carve (256B aligned)
    size_t off = 0;
    auto carve = [&](size_t bytes) -> char* {
        char* p = (char*)d_ws + off;
        off = (off + bytes + 255) & ~(size_t)255;
        return p;
    };
    float* qkvs     = (float*)carve((size_t)N * NCOLS * 4);
    float* h        = (float*)carve((size_t)N * HIDDEN * 4);
    float* Wcat     = (float*)carve(128 * NCOLS * 4);
    float* bcat     = (float*)carve(NCOLS * 4);
    int*   counts   = (int*)carve((size_t)N * 4);
    int*   row_ptr  = (int*)carve((size_t)(N + 1) * 4);
    int*   cursor   = (int*)carve((size_t)N * 4);
    int*   src_sorted = (int*)carve((size_t)E * 4);
    float* pooled   = (float*)carve((size_t)(N_GRAPHS * HIDDEN + N_GRAPHS) * 4);
    float* cntf     = pooled + N_GRAPHS * HIDDEN;

    // ---- CSR build (dst is layer-invariant) ----
    hipMemsetAsync(counts, 0, (size_t)N * 4, stream);
    hist_kernel<<<(E + 255) / 256, 256, 0, stream>>>(ei + E, counts, E);
    scan_kernel<<<1, 1024, 0, stream>>>(counts, row_ptr, cursor, N);
    scatter_kernel<<<(E + 255) / 256, 256, 0, stream>>>(ei, cursor, src_sorted, E);

    // ---- 3 TransformerConv layers ----
    for (int l = 0; l < 3; ++l) {
        int K = (l == 0) ? 128 : 64;
        const float* Ain = (l == 0) ? x : h;
        int packTot = K * NCOLS;
        pack_kernel<<<(packTot + 255) / 256, 256, 0, stream>>>(
            Wl[l][0], Wl[l][1], Wl[l][2], Wl[l][3],
            bl[l][0], bl[l][1], bl[l][2], bl[l][3], Wcat, bcat, K);
        dim3 ggrid(NCOLS / BN, (N + BM - 1) / BM);
        gemm_bias_kernel<<<ggrid, 256, 0, stream>>>(Ain, Wcat, bcat, qkvs, N, K, NCOLS);
        int do_ln = (l < 2) ? 1 : 0;
        const float* gg = (l == 0) ? g0 : g1;
        const float* bb = (l == 0) ? beta0 : beta1;
        edge_conv_kernel<<<(N + 3) / 4, 256, 0, stream>>>(
            qkvs, row_ptr, src_sorted, gg, bb, h, N, do_ln);
    }

    // ---- global mean pool + head ----
    hipMemsetAsync(pooled, 0, (size_t)(N_GRAPHS * HIDDEN + N_GRAPHS) * 4, stream);
    pool_kernel<<<(N + POOL_NODES - 1) / POOL_NODES, 64, 0, stream>>>(h, batch, pooled, cntf, N);
    final_kernel<<<1, 64, 0, stream>>>(pooled, cntf, Wp, bp, (float*)d_out);
}

// Round 3
// 729.952 us; speedup vs baseline: 1.2016x; 1.1058x over previous
//
#include <hip/hip_runtime.h>
#include <math.h>

// ---------------------------------------------------------------------------
// Problem constants (from reference)
// ---------------------------------------------------------------------------
#define HIDDEN 64
#define HEADS 2
#define NCOLS 448          // 3*HEADS*HIDDEN (q,k,v) + HIDDEN (skip)
#define N_GRAPHS 64
#define LN_EPS 1e-5f

// ---------------------------------------------------------------------------
// Weight pack: Wcat[K][448] = [Wq*0.125 | Wk | Wv | Ws], bcat[448]
// (1/sqrt(64) folded into q — exact power-of-2 scale, bitwise-neutral)
// ---------------------------------------------------------------------------
__global__ void pack_kernel(const float* __restrict__ Wq, const float* __restrict__ Wk,
                            const float* __restrict__ Wv, const float* __restrict__ Ws,
                            const float* __restrict__ bq, const float* __restrict__ bk,
                            const float* __restrict__ bv, const float* __restrict__ bs,
                            float* __restrict__ Wcat, float* __restrict__ bcat, int K)
{
    int idx = blockIdx.x * 256 + threadIdx.x;
    int total = K * NCOLS;
    if (idx < total) {
        int r = idx / NCOLS, c = idx - r * NCOLS;
        float v;
        if      (c < 128) v = Wq[r * 128 + c] * 0.125f;
        else if (c < 256) v = Wk[r * 128 + (c - 128)];
        else if (c < 384) v = Wv[r * 128 + (c - 256)];
        else              v = Ws[r * 64  + (c - 384)];
        Wcat[idx] = v;
    }
    if (idx < NCOLS) {
        float b;
        if      (idx < 128) b = bq[idx] * 0.125f;
        else if (idx < 256) b = bk[idx - 128];
        else if (idx < 384) b = bv[idx - 256];
        else                b = bs[idx - 384];
        bcat[idx] = b;
    }
}

// ---------------------------------------------------------------------------
// fp32 tiled GEMM with bias: C[M,448] = A[M,K] @ B[K,448] + bias
// BM=256, BN=64, BK=16, 256 threads, 16x4 microtile / thread.
// 64 FMA : 5 LDS b128 reads per kk -> high VALU issue fraction.
// ---------------------------------------------------------------------------
#define BM 256
#define BN 64
#define BK 16

__global__ __launch_bounds__(256) void gemm_bias_kernel(
    const float* __restrict__ A, const float* __restrict__ B,
    const float* __restrict__ bias, float* __restrict__ C,
    int M, int K, int Ncols)
{
    __shared__ __align__(16) float As[BK][BM + 4]; // k-major (transposed) A tile
    __shared__ __align__(16) float Bs[BK][BN];

    int tid = threadIdx.x;
    int tx = tid & 15;    // 0..15 -> 4 cols each
    int ty = tid >> 4;    // 0..15 -> 16 rows each
    int row0 = blockIdx.y * BM;
    int col0 = blockIdx.x * BN;

    float acc[16][4] = {};

    for (int k0 = 0; k0 < K; k0 += BK) {
        // A tile: 256 rows x 16 k = 1024 float4 chunks; 4 per thread
        #pragma unroll
        for (int i = 0; i < 4; ++i) {
            int f   = tid + i * 256;          // float4 id
            int m   = f >> 2;                 // 0..255
            int kc  = f & 3;                  // 0..3 (k-chunk of 4)
            int gr  = row0 + m;
            float4 v = make_float4(0.f, 0.f, 0.f, 0.f);
            if (gr < M) v = *(const float4*)&A[(size_t)gr * K + k0 + kc * 4];
            As[kc * 4 + 0][m] = v.x;
            As[kc * 4 + 1][m] = v.y;
            As[kc * 4 + 2][m] = v.z;
            As[kc * 4 + 3][m] = v.w;
        }
        // B tile: 16 k x 64 cols = 256 float4; 1 per thread
        {
            int kk = tid >> 4;
            int c4 = tid & 15;
            *(float4*)&Bs[kk][c4 * 4] =
                *(const float4*)&B[(size_t)(k0 + kk) * Ncols + col0 + c4 * 4];
        }
        __syncthreads();
        #pragma unroll
        for (int kk = 0; kk < BK; ++kk) {
            float4 t0 = *(const float4*)&As[kk][ty * 16 + 0];
            float4 t1 = *(const float4*)&As[kk][ty * 16 + 4];
            float4 t2 = *(const float4*)&As[kk][ty * 16 + 8];
            float4 t3 = *(const float4*)&As[kk][ty * 16 + 12];
            float4 b4 = *(const float4*)&Bs[kk][tx * 4];
            float av[16] = {t0.x, t0.y, t0.z, t0.w, t1.x, t1.y, t1.z, t1.w,
                            t2.x, t2.y, t2.z, t2.w, t3.x, t3.y, t3.z, t3.w};
            float bv[4] = {b4.x, b4.y, b4.z, b4.w};
            #pragma unroll
            for (int i = 0; i < 16; ++i)
                #pragma unroll
                for (int j = 0; j < 4; ++j)
                    acc[i][j] = fmaf(av[i], bv[j], acc[i][j]);
        }
        __syncthreads();
    }

    float4 bsv = *(const float4*)&bias[col0 + tx * 4];
    float bb[4] = {bsv.x, bsv.y, bsv.z, bsv.w};
    #pragma unroll
    for (int i = 0; i < 16; ++i) {
        int r = row0 + ty * 16 + i;
        if (r >= M) continue;
        float4 o = make_float4(acc[i][0] + bb[0], acc[i][1] + bb[1],
                               acc[i][2] + bb[2], acc[i][3] + bb[3]);
        *(float4*)&C[(size_t)r * Ncols + col0 + tx * 4] = o;
    }
}

// ---------------------------------------------------------------------------
// CSR build: histogram -> 3-kernel parallel scan -> scatter
// ---------------------------------------------------------------------------
__global__ void hist_kernel(const int* __restrict__ dst, int* __restrict__ counts, int E)
{
    int i = blockIdx.x * 256 + threadIdx.x;
    if (i < E) atomicAdd(&counts[dst[i]], 1);
}

__global__ __launch_bounds__(256) void block_reduce_kernel(
    const int* __restrict__ counts, int* __restrict__ bsum, int N)
{
    __shared__ int s[256];
    int t = threadIdx.x;
    int i = blockIdx.x * 256 + t;
    s[t] = (i < N) ? counts[i] : 0;
    __syncthreads();
    #pragma unroll
    for (int o = 128; o; o >>= 1) {
        if (t < o) s[t] += s[t + o];
        __syncthreads();
    }
    if (t == 0) bsum[blockIdx.x] = s[0];
}

__global__ __launch_bounds__(256) void scan_partials_kernel(
    const int* __restrict__ bsum, int* __restrict__ boff, int nb, int* __restrict__ rowN)
{
    __shared__ int s[256];
    int t = threadIdx.x;
    int v = (t < nb) ? bsum[t] : 0;
    s[t] = v;
    __syncthreads();
    #pragma unroll
    for (int o = 1; o < 256; o <<= 1) {
        int x = (t >= o) ? s[t - o] : 0;
        __syncthreads();
        s[t] += x;
        __syncthreads();
    }
    if (t < nb) boff[t] = s[t] - v;     // exclusive
    if (t == nb - 1) rowN[0] = s[t];    // total = row_ptr[N]
}

__global__ __launch_bounds__(256) void block_scan_kernel(
    const int* __restrict__ counts, const int* __restrict__ boff,
    int* __restrict__ row_ptr, int* __restrict__ cursor, int N)
{
    __shared__ int s[256];
    int t = threadIdx.x;
    int i = blockIdx.x * 256 + t;
    int v = (i < N) ? counts[i] : 0;
    s[t] = v;
    __syncthreads();
    #pragma unroll
    for (int o = 1; o < 256; o <<= 1) {
        int x = (t >= o) ? s[t - o] : 0;
        __syncthreads();
        s[t] += x;
        __syncthreads();
    }
    if (i < N) {
        int excl = s[t] - v + boff[blockIdx.x];
        row_ptr[i] = excl;
        cursor[i]  = excl;
    }
}

__global__ void scatter_kernel(const int* __restrict__ ei, int* __restrict__ cursor,
                               int* __restrict__ src_sorted, int E)
{
    int i = blockIdx.x * 256 + threadIdx.x;
    if (i < E) {
        int d = ei[E + i];                    // dst
        int pos = atomicAdd(&cursor[d], 1);
        src_sorted[pos] = ei[i];              // src
    }
}

// ---------------------------------------------------------------------------
// DPP 16-lane sum: quad_perm xor1, xor2, row_half_mirror, row_mirror.
// Pure VALU — no LDS pipe, no lgkmcnt waits.
// ---------------------------------------------------------------------------
__device__ __forceinline__ float dpp_sum16(float x)
{
    float t;
    t = __int_as_float(__builtin_amdgcn_mov_dpp(__float_as_int(x), 0xB1,  0xF, 0xF, true)); x += t; // xor 1
    t = __int_as_float(__builtin_amdgcn_mov_dpp(__float_as_int(x), 0x4E,  0xF, 0xF, true)); x += t; // xor 2
    t = __int_as_float(__builtin_amdgcn_mov_dpp(__float_as_int(x), 0x141, 0xF, 0xF, true)); x += t; // half-mirror
    t = __int_as_float(__builtin_amdgcn_mov_dpp(__float_as_int(x), 0x140, 0xF, 0xF, true)); x += t; // row-mirror
    return x;
}

// ---------------------------------------------------------------------------
// Fused edge kernel: one wave per dst node, 4 edge-groups x 16 lanes.
// Register double-buffered K/V gathers; DPP dot-reduce; flash-state merge;
// head-mean + skip + ReLU + optional LN.
// qkvs row layout: [q_h0(64, pre-scaled) q_h1(64) k_h0 k_h1 v_h0 v_h1 skip(64)]
// ---------------------------------------------------------------------------
__global__ __launch_bounds__(256) void edge_conv_kernel(
    const float* __restrict__ qkvs, const int* __restrict__ row_ptr,
    const int* __restrict__ src_sorted, const float* __restrict__ gamma,
    const float* __restrict__ beta, float* __restrict__ hout, int N, int do_ln)
{
    int wave = threadIdx.x >> 6;
    int lane = threadIdx.x & 63;
    int g    = lane >> 4;        // edge-group 0..3
    int sub  = lane & 15;        // dim-chunk 0..15 (4 dims each)
    int node = blockIdx.x * 4 + wave;
    if (node >= N) return;

    const float* base = qkvs + (size_t)node * NCOLS;
    float4 q0 = *(const float4*)&base[sub * 4];        // pre-scaled by 1/8
    float4 q1 = *(const float4*)&base[64 + sub * 4];

    int e0 = row_ptr[node], e1 = row_ptr[node + 1];

    float  m0 = -1e30f, m1 = -1e30f;
    float  s0 = 0.f, s1 = 0.f;
    float4 a0 = make_float4(0.f, 0.f, 0.f, 0.f);
    float4 a1 = make_float4(0.f, 0.f, 0.f, 0.f);

    int  e    = e0 + g;
    bool have = (e < e1);
    float4 k0c, k1c, v0c, v1c;
    if (have) {
        const float* jb = qkvs + (size_t)src_sorted[e] * NCOLS;
        k0c = *(const float4*)&jb[128 + sub * 4];
        k1c = *(const float4*)&jb[192 + sub * 4];
        v0c = *(const float4*)&jb[256 + sub * 4];
        v1c = *(const float4*)&jb[320 + sub * 4];
    }

    while (have) {
        int  en    = e + 4;
        bool haven = (en < e1);
        float4 k0n, k1n, v0n, v1n;
        if (haven) {
            const float* jbn = qkvs + (size_t)src_sorted[en] * NCOLS;
            k0n = *(const float4*)&jbn[128 + sub * 4];
            k1n = *(const float4*)&jbn[192 + sub * 4];
            v0n = *(const float4*)&jbn[256 + sub * 4];
            v1n = *(const float4*)&jbn[320 + sub * 4];
        }

        float p0 = fmaf(q0.w, k0c.w, fmaf(q0.z, k0c.z, fmaf(q0.y, k0c.y, q0.x * k0c.x)));
        float p1 = fmaf(q1.w, k1c.w, fmaf(q1.z, k1c.z, fmaf(q1.y, k1c.y, q1.x * k1c.x)));
        float sc0 = dpp_sum16(p0);
        float sc1 = dpp_sum16(p1);

        float nm0 = fmaxf(m0, sc0);
        float f0  = __expf(m0 - nm0);
        float w0  = __expf(sc0 - nm0);
        s0 = fmaf(s0, f0, w0);
        a0.x = fmaf(a0.x, f0, w0 * v0c.x);
        a0.y = fmaf(a0.y, f0, w0 * v0c.y);
        a0.z = fmaf(a0.z, f0, w0 * v0c.z);
        a0.w = fmaf(a0.w, f0, w0 * v0c.w);
        m0 = nm0;

        float nm1 = fmaxf(m1, sc1);
        float f1  = __expf(m1 - nm1);
        float w1  = __expf(sc1 - nm1);
        s1 = fmaf(s1, f1, w1);
        a1.x = fmaf(a1.x, f1, w1 * v1c.x);
        a1.y = fmaf(a1.y, f1, w1 * v1c.y);
        a1.z = fmaf(a1.z, f1, w1 * v1c.z);
        a1.w = fmaf(a1.w, f1, w1 * v1c.w);
        m1 = nm1;

        k0c = k0n; k1c = k1n; v0c = v0n; v1c = v1n;
        e = en; have = haven;
    }

    // merge flash states across the 4 groups (xor 16, then 32)
    #pragma unroll
    for (int off = 16; off <= 32; off <<= 1) {
        float mo0 = __shfl_xor(m0, off);
        float so0 = __shfl_xor(s0, off);
        float4 ao0;
        ao0.x = __shfl_xor(a0.x, off); ao0.y = __shfl_xor(a0.y, off);
        ao0.z = __shfl_xor(a0.z, off); ao0.w = __shfl_xor(a0.w, off);
        float nm = fmaxf(m0, mo0);
        float fa = __expf(m0 - nm), fb = __expf(mo0 - nm);
        s0 = s0 * fa + so0 * fb;
        a0.x = a0.x * fa + ao0.x * fb; a0.y = a0.y * fa + ao0.y * fb;
        a0.z = a0.z * fa + ao0.z * fb; a0.w = a0.w * fa + ao0.w * fb;
        m0 = nm;

        float mo1 = __shfl_xor(m1, off);
        float so1 = __shfl_xor(s1, off);
        float4 ao1;
        ao1.x = __shfl_xor(a1.x, off); ao1.y = __shfl_xor(a1.y, off);
        ao1.z = __shfl_xor(a1.z, off); ao1.w = __shfl_xor(a1.w, off);
        nm = fmaxf(m1, mo1);
        fa = __expf(m1 - nm); fb = __expf(mo1 - nm);
        s1 = s1 * fa + so1 * fb;
        a1.x = a1.x * fa + ao1.x * fb; a1.y = a1.y * fa + ao1.y * fb;
        a1.z = a1.z * fa + ao1.z * fb; a1.w = a1.w * fa + ao1.w * fb;
        m1 = nm;
    }

    float4 skip = *(const float4*)&base[384 + sub * 4];
    float4 o;
    if (e1 > e0) {
        float r0 = 0.5f / s0, r1 = 0.5f / s1;
        o.x = a0.x * r0 + a1.x * r1 + skip.x;
        o.y = a0.y * r0 + a1.y * r1 + skip.y;
        o.z = a0.z * r0 + a1.z * r1 + skip.z;
        o.w = a0.w * r0 + a1.w * r1 + skip.w;
    } else {
        o = skip;
    }
    o.x = fmaxf(o.x, 0.f); o.y = fmaxf(o.y, 0.f);
    o.z = fmaxf(o.z, 0.f); o.w = fmaxf(o.w, 0.f);

    if (do_ln) {
        float mu = dpp_sum16(o.x + o.y + o.z + o.w) * (1.0f / 64.0f);
        float dx = o.x - mu, dy = o.y - mu, dz = o.z - mu, dw = o.w - mu;
        float var = dpp_sum16(dx * dx + dy * dy + dz * dz + dw * dw) * (1.0f / 64.0f);
        float rs = rsqrtf(var + LN_EPS);
        float4 gm = *(const float4*)&gamma[sub * 4];
        float4 bt = *(const float4*)&beta[sub * 4];
        o.x = dx * rs * gm.x + bt.x;
        o.y = dy * rs * gm.y + bt.y;
        o.z = dz * rs * gm.z + bt.z;
        o.w = dw * rs * gm.w + bt.w;
    }
    if (g == 0)
        *(float4*)&hout[(size_t)node * HIDDEN + sub * 4] = o;
}

// ---------------------------------------------------------------------------
// Pooling: batch is sorted; per-block register accumulation, rare atomic flush
// ---------------------------------------------------------------------------
#define POOL_NODES 256
__global__ __launch_bounds__(64) void pool_kernel(const float* __restrict__ h,
                                                  const int* __restrict__ batch,
                                                  float* __restrict__ pooled,
                                                  float* __restrict__ cnt, int N)
{
    int lane = threadIdx.x;
    int start = blockIdx.x * POOL_NODES;
    if (start >= N) return;
    int end = min(start + POOL_NODES, N);
    float acc = 0.f;
    int cur = batch[start];
    int c = 0;
    for (int i = start; i < end; ++i) {
        int b = batch[i];
        if (b != cur) {
            atomicAdd(&pooled[cur * HIDDEN + lane], acc);
            if (lane == 0) atomicAdd(&cnt[cur], (float)c);
            acc = 0.f; c = 0; cur = b;
        }
        acc += h[(size_t)i * HIDDEN + lane];
        ++c;
    }
    atomicAdd(&pooled[cur * HIDDEN + lane], acc);
    if (lane == 0) atomicAdd(&cnt[cur], (float)c);
}

__global__ void final_kernel(const float* __restrict__ pooled, const float* __restrict__ cnt,
                             const float* __restrict__ Wp, const float* __restrict__ bp,
                             float* __restrict__ out)
{
    int g = threadIdx.x;   // 64 graphs
    float c = fmaxf(cnt[g], 1.0f);
    float s = 0.f;
    for (int d = 0; d < HIDDEN; ++d) s += pooled[g * HIDDEN + d] * Wp[d];
    out[g] = s / c + bp[0];
}

// ---------------------------------------------------------------------------
// Host launcher
// ---------------------------------------------------------------------------
extern "C" void kernel_launch(void* const* d_in, const int* in_sizes, int n_in,
                              void* d_out, int out_size, void* d_ws, size_t ws_size,
                              hipStream_t stream)
{
    const float* x    = (const float*)d_in[0];
    const int*   ei   = (const int*)d_in[1];
    const int*   batch= (const int*)d_in[2];

    const float* Wl[3][4];  // Wq, Wk, Wv, Ws
    const float* bl[3][4];  // bq, bk, bv, bs
    for (int l = 0; l < 3; ++l) {
        int b = 3 + l * 8;
        Wl[l][0] = (const float*)d_in[b + 0]; bl[l][0] = (const float*)d_in[b + 1];
        Wl[l][1] = (const float*)d_in[b + 2]; bl[l][1] = (const float*)d_in[b + 3];
        Wl[l][2] = (const float*)d_in[b + 4]; bl[l][2] = (const float*)d_in[b + 5];
        Wl[l][3] = (const float*)d_in[b + 6]; bl[l][3] = (const float*)d_in[b + 7];
    }
    const float* g0    = (const float*)d_in[27];
    const float* beta0 = (const float*)d_in[28];
    const float* g1    = (const float*)d_in[29];
    const float* beta1 = (const float*)d_in[30];
    const float* Wp    = (const float*)d_in[31];
    const float* bp    = (const float*)d_in[32];

    const int N = in_sizes[0] / 128;   // 50000
    const int E = in_sizes[1] / 2;     // 800000

    // workspace carve (256B aligned)
    size_t off = 0;
    auto carve = [&](size_t bytes) -> char* {
        char* p = (char*)d_ws + off;
        off = (off + bytes + 255) & ~(size_t)255;
        return p;
    };
    float* qkvs     = (float*)carve((size_t)N * NCOLS * 4);
    float* h        = (float*)carve((size_t)N * HIDDEN * 4);
    float* Wcat     = (float*)carve(128 * NCOLS * 4);
    float* bcat     = (float*)carve(NCOLS * 4);
    int*   counts   = (int*)carve((size_t)N * 4);
    int*   row_ptr  = (int*)carve((size_t)(N + 1) * 4);
    int*   cursor   = (int*)carve((size_t)N * 4);
    int*   src_sorted = (int*)carve((size_t)E * 4);
    int*   bsum     = (int*)carve(1024 * 4);
    int*   boff     = (int*)carve(1024 * 4);
    float* pooled   = (float*)carve((size_t)(N_GRAPHS * HIDDEN + N_GRAPHS) * 4);
    float* cntf     = pooled + N_GRAPHS * HIDDEN;

    const int nb = (N + 255) / 256;    // 196 scan blocks

    // ---- CSR build (dst is layer-invariant) ----
    hipMemsetAsync(counts, 0, (size_t)N * 4, stream);
    hist_kernel<<<(E + 255) / 256, 256, 0, stream>>>(ei + E, counts, E);
    block_reduce_kernel<<<nb, 256, 0, stream>>>(counts, bsum, N);
    scan_partials_kernel<<<1, 256, 0, stream>>>(bsum, boff, nb, &row_ptr[N]);
    block_scan_kernel<<<nb, 256, 0, stream>>>(counts, boff, row_ptr, cursor, N);
    scatter_kernel<<<(E + 255) / 256, 256, 0, stream>>>(ei, cursor, src_sorted, E);

    // ---- 3 TransformerConv layers ----
    for (int l = 0; l < 3; ++l) {
        int K = (l == 0) ? 128 : 64;
        const float* Ain = (l == 0) ? x : h;
        int packTot = K * NCOLS;
        pack_kernel<<<(packTot + 255) / 256, 256, 0, stream>>>(
            Wl[l][0], Wl[l][1], Wl[l][2], Wl[l][3],
            bl[l][0], bl[l][1], bl[l][2], bl[l][3], Wcat, bcat, K);
        dim3 ggrid(NCOLS / BN, (N + BM - 1) / BM);
        gemm_bias_kernel<<<ggrid, 256, 0, stream>>>(Ain, Wcat, bcat, qkvs, N, K, NCOLS);
        int do_ln = (l < 2) ? 1 : 0;
        const float* gg = (l == 0) ? g0 : g1;
        const float* bb = (l == 0) ? beta0 : beta1;
        edge_conv_kernel<<<(N + 3) / 4, 256, 0, stream>>>(
            qkvs, row_ptr, src_sorted, gg, bb, h, N, do_ln);
    }

    // ---- global mean pool + head ----
    hipMemsetAsync(pooled, 0, (size_t)(N_GRAPHS * HIDDEN + N_GRAPHS) * 4, stream);
    pool_kernel<<<(N + POOL_NODES - 1) / POOL_NODES, 64, 0, stream>>>(h, batch, pooled, cntf, N);
    final_kernel<<<1, 64, 0, stream>>>(pooled, cntf, Wp, bp, (float*)d_out);
}